// Round 17
// baseline (2319.909 us; speedup 1.0000x reference)
//
#include <hip/hip_runtime.h>

// LSTMFromEmbeddings: B=128, T=1024, E=256, H=256, C=2, bidirectional + meanpool + linear.
//
// R16 = R14 (best passing: transposed MFMA, gates in-lane, 1 lgkm barrier/step, proven
// tagged-word sync, 2-step parity unroll) with the X TILE MOVED OUT OF LDS:
// each lane loads its 8 B-fragments of x(t+1) straight from the pre-swizzled img
// (L2-resident) at step top -> xg MFMA is register-only. Halves the LDS read pole
// (R14's largest pipe cost) while keeping 8 waves / 2-per-SIMD latency hiding
// (R15 showed 1 wave/SIMD loses more than LDS sharing gains).
//  rec: 64 wgs = 16 groups (2 dir x 8 batch-blocks of 16) x 4 members (64 units).
//  prep: bf16(x*mask) image in B-fragment layout (rotation swizzle pre-applied).
//  head: out = (hsum/1024) @ W_lin^T + b_lin.

#define B_ 128
#define T_ 1024
#define E_ 256
#define H_ 256

typedef short short8 __attribute__((ext_vector_type(8)));
typedef float f32x4 __attribute__((ext_vector_type(4)));
typedef float f32x2 __attribute__((ext_vector_type(2)));

__device__ __forceinline__ unsigned short f2bf(float f) {
  unsigned u = __builtin_bit_cast(unsigned, f);
  u += 0x7fffu + ((u >> 16) & 1u);  // RNE
  return (unsigned short)(u >> 16);
}
__device__ __forceinline__ f32x4 mfma16(short8 a, short8 b, f32x4 c) {
  return __builtin_amdgcn_mfma_f32_16x16x32_bf16(a, b, c, 0, 0, 0);
}
__device__ __forceinline__ float rcpf(float x) { return __builtin_amdgcn_rcpf(x); }

// proven R8 elementwise: 5 exp + 3 rcp per unit
__device__ __forceinline__ float lstm_ew(float gi, float gf, float gg, float go, float& c) {
  float ei = __expf(-gi), ef = __expf(-gf), eg = __expf(-2.f * gg);
  float di = 1.f + ei, df = 1.f + ef, dg = 1.f + eg;
  float r1 = rcpf(di * dg);
  float si = r1 * dg;
  float tg = 2.f * (r1 * di) - 1.f;
  c = rcpf(df) * c + si * tg;
  float eo = __expf(-go), ec = __expf(2.f * c);
  float do_ = 1.f + eo, dc = 1.f + ec;
  float r3 = rcpf(do_ * dc);
  float so = r3 * dc;
  float th = 1.f - 2.f * (r3 * do_);
  return so * th;
}

__device__ __forceinline__ short8 cvt8(f32x4 v0, f32x4 v1) {
  short8 o;
  o[0] = (short)f2bf(v0[0]); o[1] = (short)f2bf(v0[1]);
  o[2] = (short)f2bf(v0[2]); o[3] = (short)f2bf(v0[3]);
  o[4] = (short)f2bf(v1[0]); o[5] = (short)f2bf(v1[1]);
  o[6] = (short)f2bf(v1[2]); o[7] = (short)f2bf(v1[3]);
  return o;
}

__device__ __forceinline__ void bar_lds() {  // LDS-only barrier; vmem stays in flight
  asm volatile("s_waitcnt lgkmcnt(0)" ::: "memory");
  __builtin_amdgcn_s_barrier();
}

// ---------------- prep: x image in B-fragment layout (rotation swizzle) ------
// word gid = (bblk*1024 + t)*512 + r*32 + s; slot s holds chunk (s - r) & 31.
__global__ __launch_bounds__(256, 4) void prep_kernel(
    const float* __restrict__ x, const float* __restrict__ mask,
    unsigned short* __restrict__ img) {
  int gid = blockIdx.x * 256 + threadIdx.x;
  int i = gid & 511;
  int tt = (gid >> 9) & 1023;
  int bblk = gid >> 19;
  int r = i >> 5, s = i & 31, kc = (s - r) & 31;
  int b = bblk * 16 + r;
  const f32x4* src = (const f32x4*)(x + ((size_t)b * T_ + tt) * E_ + kc * 8);
  float mk = mask[(size_t)b * T_ + tt];
  ((short8*)img)[gid] = cvt8(src[0] * mk, src[1] * mk);
}

// step body, compile-time parity PAR: hh reads HS[PAR] (LDS); xb loads x(t+1)
// from img (global, register-only xg); writes HS[1-PAR]; Hbuf parity (1-PAR).
#define REC_STEP(PAR, TT, MORE_)                                                \
  {                                                                             \
    const bool more_ = (MORE_);                                                 \
    short8 xb[8];                                                               \
    if (more_) {                                                                \
      if constexpr (PREP) {                                                     \
        const char* gt = gx;  /* tile of x(t+1), pre-swizzled */                \
        _Pragma("unroll") for (int j = 0; j < 8; ++j)                           \
          xb[j] = *(const short8*)(gt + ro[j]);                                 \
        gx += dstep;                                                            \
      } else {                                                                  \
        int ts = d ? (T_ - 2 - (TT)) : ((TT) + 1);                              \
        const float* xr = x + ((size_t)gb_l * T_ + ts) * E_;                    \
        float mkv = mask[(size_t)gb_l * T_ + ts];                               \
        _Pragma("unroll") for (int kp = 0; kp < 4; ++kp) {                      \
          int c0 = kp * 8 + l4, c1 = kp * 8 + 4 + l4;                           \
          f32x4 a0 = ((const f32x4*)(xr + c0 * 8))[0] * mkv;                    \
          f32x4 a1 = ((const f32x4*)(xr + c0 * 8))[1] * mkv;                    \
          f32x4 b0v = ((const f32x4*)(xr + c1 * 8))[0] * mkv;                   \
          f32x4 b1v = ((const f32x4*)(xr + c1 * 8))[1] * mkv;                   \
          xb[2 * kp] = cvt8(a0, a1);                                            \
          xb[2 * kp + 1] = cvt8(b0v, b1v);                                      \
        }                                                                       \
      }                                                                         \
    }                                                                           \
    {                                                                           \
      const char* hsP = (const char*)HS[PAR];                                   \
      _Pragma("unroll") for (int kp = 0; kp < 4; ++kp) {                        \
        short8 b0 = *(const short8*)(hsP + ro[2 * kp]);                         \
        short8 b1 = *(const short8*)(hsP + ro[2 * kp + 1]);                     \
        acc[0] = mfma16(wh[0][2 * kp], b0, acc[0]);                             \
        acc[1] = mfma16(wh[1][2 * kp], b0, acc[1]);                             \
        accB[0] = mfma16(wh[0][2 * kp + 1], b1, accB[0]);                       \
        accB[1] = mfma16(wh[1][2 * kp + 1], b1, accB[1]);                       \
      }                                                                         \
    }                                                                           \
    float h0 = lstm_ew(acc[0][0] + accB[0][0], acc[0][1] + accB[0][1],          \
                       acc[0][2] + accB[0][2], acc[0][3] + accB[0][3], cs[0]);  \
    float h1 = lstm_ew(acc[1][0] + accB[1][0], acc[1][1] + accB[1][1],          \
                       acc[1][2] + accB[1][2], acc[1][3] + accB[1][3], cs[1]);  \
    hsums[0] += h0;                                                             \
    hsums[1] += h1;                                                             \
    if (more_) {                                                                \
      const unsigned tag = (unsigned)((TT) + 1);                                \
      unsigned long long* __restrict__ hb = (PAR) ? Hb0 : Hb1;                  \
      unsigned pay;                                                             \
      asm("v_cvt_pk_bf16_f32 %0, %1, %2" : "=v"(pay) : "v"(h0), "v"(h1));       \
      unsigned long long wrd = (((unsigned long long)tag) << 32) | (unsigned long long)pay; \
      __hip_atomic_store(&hb[pubIdx], wrd, __ATOMIC_RELAXED,                    \
                         __HIP_MEMORY_SCOPE_AGENT);                             \
      asm volatile("" ::: "memory");                                            \
      *(int*)((char*)HS[1 - (PAR)] + ownOff) = (int)pay;                        \
      acc[0] = bias4[0];                                                        \
      acc[1] = bias4[1];                                                        \
      accB[0] = (f32x4){0.f, 0.f, 0.f, 0.f};                                    \
      accB[1] = (f32x4){0.f, 0.f, 0.f, 0.f};                                    \
      _Pragma("unroll") for (int kp = 0; kp < 4; ++kp) {                        \
        acc[0] = mfma16(wi[0][2 * kp], xb[2 * kp], acc[0]);                     \
        acc[1] = mfma16(wi[1][2 * kp], xb[2 * kp], acc[1]);                     \
        accB[0] = mfma16(wi[0][2 * kp + 1], xb[2 * kp + 1], accB[0]);           \
        accB[1] = mfma16(wi[1][2 * kp + 1], xb[2 * kp + 1], accB[1]);           \
      }                                                                         \
      unsigned long long v0 = __hip_atomic_load(&hb[p0], __ATOMIC_RELAXED,      \
                                                __HIP_MEMORY_SCOPE_AGENT);      \
      unsigned long long v1 = __hip_atomic_load(&hb[p1], __ATOMIC_RELAXED,      \
                                                __HIP_MEMORY_SCOPE_AGENT);      \
      unsigned long long v2 = __hip_atomic_load(&hb[p2], __ATOMIC_RELAXED,      \
                                                __HIP_MEMORY_SCOPE_AGENT);      \
      asm volatile("" ::: "memory");                                            \
      while (((unsigned)(v0 >> 32) != tag) | ((unsigned)(v1 >> 32) != tag) |    \
             ((unsigned)(v2 >> 32) != tag)) {                                   \
        if ((unsigned)(v0 >> 32) != tag)                                        \
          v0 = __hip_atomic_load(&hb[p0], __ATOMIC_RELAXED, __HIP_MEMORY_SCOPE_AGENT); \
        if ((unsigned)(v1 >> 32) != tag)                                        \
          v1 = __hip_atomic_load(&hb[p1], __ATOMIC_RELAXED, __HIP_MEMORY_SCOPE_AGENT); \
        if ((unsigned)(v2 >> 32) != tag)                                        \
          v2 = __hip_atomic_load(&hb[p2], __ATOMIC_RELAXED, __HIP_MEMORY_SCOPE_AGENT); \
        asm volatile("" ::: "memory");                                          \
      }                                                                         \
      char* hw = (char*)HS[1 - (PAR)];                                          \
      *(int*)(hw + uo0) = (int)(unsigned)v0;                                    \
      *(int*)(hw + uo1) = (int)(unsigned)v1;                                    \
      *(int*)(hw + uo2) = (int)(unsigned)v2;                                    \
      bar_lds();                                                                \
    }                                                                           \
  }

// ---------------- rec: fused projection + recurrence --------------------------
// grid 64, 512 threads (8 waves, 2/SIMD). g = bid & 15, m = bid >> 4.
// Member m owns units [m*64, m*64+64). A-row map (R13): tile T = 2w+i, row l15:
// gate = l15&3, unit = w*8 + (l15>>2)*2 + i; D: acc[i][r] = gate r of unit
// w*8+l4*2+i, batch l15.
template <bool PREP>
__global__ __launch_bounds__(512, 1) void rec_kernel(
    const float* __restrict__ x, const float* __restrict__ mask,
    const unsigned short* __restrict__ img,
    const float* __restrict__ WihF, const float* __restrict__ WhhF,
    const float* __restrict__ bF, const float* __restrict__ WihB,
    const float* __restrict__ WhhB, const float* __restrict__ bB,
    unsigned long long* __restrict__ Hbuf, float* __restrict__ hsum) {
  __shared__ __align__(16) short HS[2][16 * 256];  // h stage, parity dbuf (16KB)

  const int bid = blockIdx.x;
  const int g = bid & 15, m = bid >> 4;
  const int d = g >> 3, bblk = g & 7;
  const int tid = threadIdx.x;
  const int w = tid >> 6, l = tid & 63, l15 = l & 15, l4 = l >> 4;
  const int gb_l = bblk * 16 + l15;  // this lane's batch (B-fragment row)

  const float* Wih = d ? WihB : WihF;
  const float* Whh = d ? WhhB : WhhF;
  const float* bias = d ? bB : bF;

  // ---- weight A-fragments -> registers (R13 row map) ----
  short8 wi[2][8], wh[2][8];
#pragma unroll
  for (int i = 0; i < 2; ++i) {
    int u_row = w * 8 + (l15 >> 2) * 2 + i;
    size_t nat = (size_t)((l15 & 3) * 256 + m * 64 + u_row);
#pragma unroll
    for (int kb = 0; kb < 8; ++kb) {
      const f32x4* pi = (const f32x4*)(Wih + nat * E_ + kb * 32 + l4 * 8);
      wi[i][kb] = cvt8(pi[0], pi[1]);
      const f32x4* ph = (const f32x4*)(Whh + nat * H_ + kb * 32 + l4 * 8);
      wh[i][kb] = cvt8(ph[0], ph[1]);
    }
  }
  f32x4 bias4[2];
#pragma unroll
  for (int i = 0; i < 2; ++i)
#pragma unroll
    for (int r = 0; r < 4; ++r)
      bias4[i][r] = bias[r * 256 + m * 64 + w * 8 + l4 * 2 + i];

  // ---- precomputed lane constants ----
  // B-fragment byte offsets (rotation swizzle): row l15, chunk c ->
  //   l15*512 + ((c+l15)&31)*16   (valid for both HS tiles and img tiles)
  int ro[8];
#pragma unroll
  for (int kp = 0; kp < 4; ++kp) {
    ro[2 * kp] = l15 * 512 + ((((kp * 8 + l4) + l15) & 31) << 4);
    ro[2 * kp + 1] = l15 * 512 + ((((kp * 8 + 4 + l4) + l15) & 31) << 4);
  }
  // publish word index (uw = m*32+w*4+l4, batch-minor -> coalesced)
  const int pubIdx = (m * 32 + w * 4 + l4) * 16 + l15;
  // own HS byte offset: unit chunk c = m*8+w, batch l15, sub l4*4
  const int ownOff = l15 * 512 + ((((m * 8 + w) + l15) & 31) << 4) + l4 * 4;
  // poll phys words (3/thread, skip own member's 512-block)
  int pp = tid * 3;
  const int p0 = pp + (pp >= m * 512 ? 512 : 0);
  const int p1 = pp + 1 + (pp + 1 >= m * 512 ? 512 : 0);
  const int p2 = pp + 2 + (pp + 2 >= m * 512 ? 512 : 0);
  // unpack byte offsets: word p = uw*16+b -> HS[b], chunk uw>>2, sub (uw&3)*4
#define UOFF(p) (((p) & 15) * 512 + (((((p) >> 6) + ((p) & 15)) & 31) << 4) + ((((p) >> 4) & 3) * 4))
  const int uo0 = UOFF(p0), uo1 = UOFF(p1), uo2 = UOFF(p2);
#undef UOFF
  // Hbuf parity bases
  unsigned long long* __restrict__ Hb0 = Hbuf + ((size_t)g * 2 + 0) * 2048;
  unsigned long long* __restrict__ Hb1 = Hbuf + ((size_t)g * 2 + 1) * 2048;

  // img pointers: tile t at imgB + (bblk*1024 + t)*8192
  const int dstep = d ? -8192 : 8192;
  const char* imgB = (const char*)img;
  const char* gx = imgB + ((size_t)(bblk * 1024 + (d ? (T_ - 2) : 1))) * 8192;

  // ---- prologue: HS[0]=0; acc = bias + xg_0 (x_0 from img/global, reg-only) --
  ((int4*)HS)[tid] = (int4){0, 0, 0, 0};  // zeros HS[0] (8KB)
  __syncthreads();  // HS[0] zeros visible

  f32x4 acc[2], accB[2];
  acc[0] = bias4[0];
  acc[1] = bias4[1];
  accB[0] = (f32x4){0.f, 0.f, 0.f, 0.f};
  accB[1] = (f32x4){0.f, 0.f, 0.f, 0.f};
  if constexpr (PREP) {
    const char* gt0 = imgB + ((size_t)(bblk * 1024 + (d ? (T_ - 1) : 0))) * 8192;
#pragma unroll
    for (int kp = 0; kp < 4; ++kp) {
      short8 b0 = *(const short8*)(gt0 + ro[2 * kp]);
      short8 b1 = *(const short8*)(gt0 + ro[2 * kp + 1]);
      acc[0] = mfma16(wi[0][2 * kp], b0, acc[0]);
      acc[1] = mfma16(wi[1][2 * kp], b0, acc[1]);
      accB[0] = mfma16(wi[0][2 * kp + 1], b1, accB[0]);
      accB[1] = mfma16(wi[1][2 * kp + 1], b1, accB[1]);
    }
  } else {
    int ts = d ? (T_ - 1) : 0;
    const float* xr = x + ((size_t)gb_l * T_ + ts) * E_;
    float mkv = mask[(size_t)gb_l * T_ + ts];
#pragma unroll
    for (int kp = 0; kp < 4; ++kp) {
      int c0 = kp * 8 + l4, c1 = kp * 8 + 4 + l4;
      f32x4 a0 = ((const f32x4*)(xr + c0 * 8))[0] * mkv;
      f32x4 a1 = ((const f32x4*)(xr + c0 * 8))[1] * mkv;
      f32x4 b0v = ((const f32x4*)(xr + c1 * 8))[0] * mkv;
      f32x4 b1v = ((const f32x4*)(xr + c1 * 8))[1] * mkv;
      short8 b0 = cvt8(a0, a1);
      short8 b1 = cvt8(b0v, b1v);
      acc[0] = mfma16(wi[0][2 * kp], b0, acc[0]);
      acc[1] = mfma16(wi[1][2 * kp], b0, acc[1]);
      accB[0] = mfma16(wi[0][2 * kp + 1], b1, accB[0]);
      accB[1] = mfma16(wi[1][2 * kp + 1], b1, accB[1]);
    }
  }

  float cs[2] = {0.f, 0.f};
  float hsums[2] = {0.f, 0.f};

  for (int t2 = 0; t2 < 511; ++t2) {
    const int tt = t2 * 2;
    REC_STEP(0, tt, true);
    REC_STEP(1, tt + 1, true);
  }
  REC_STEP(0, 1022, true);
  REC_STEP(1, 1023, false);

  // pooled sums: lane owns (batch gb_l, units gu, gu+1) — 8B store
  {
    int gu = m * 64 + w * 8 + l4 * 2;
    *(f32x2*)(hsum + ((size_t)d * B_ + gb_l) * H_ + gu) = (f32x2){hsums[0], hsums[1]};
  }
}

// ---------------- head: linear ----------------------------------------------
__global__ __launch_bounds__(256, 1) void head_kernel(
    const float* __restrict__ hsum, const float* __restrict__ Wlin,
    const float* __restrict__ blin, float* __restrict__ out) {
  int tid = threadIdx.x;  // 256 = 128 b x 2 c
  int b = tid >> 1, c = tid & 1;
  const f32x4* hf = (const f32x4*)(hsum + (size_t)b * H_);
  const f32x4* hbk = (const f32x4*)(hsum + (size_t)B_ * H_ + (size_t)b * H_);
  const f32x4* wl = (const f32x4*)(Wlin + (size_t)c * 512);
  float s = 0.f;
  for (int j = 0; j < 64; ++j) {
    f32x4 a = hf[j], ww = wl[j];
    s += a[0] * ww[0] + a[1] * ww[1] + a[2] * ww[2] + a[3] * ww[3];
  }
  for (int j = 0; j < 64; ++j) {
    f32x4 a = hbk[j], ww = wl[64 + j];
    s += a[0] * ww[0] + a[1] * ww[1] + a[2] * ww[2] + a[3] * ww[3];
  }
  out[tid] = s * (1.0f / 1024.0f) + blin[c];
}

// ---------------- launch -----------------------------------------------------
extern "C" void kernel_launch(void* const* d_in, const int* in_sizes, int n_in,
                              void* d_out, int out_size, void* d_ws, size_t ws_size,
                              hipStream_t stream) {
  const float* emb = (const float*)d_in[0];
  const float* mask = (const float*)d_in[1];
  const float* Wih_f = (const float*)d_in[2];
  const float* Whh_f = (const float*)d_in[3];
  const float* b_f = (const float*)d_in[4];
  const float* Wih_b = (const float*)d_in[5];
  const float* Whh_b = (const float*)d_in[6];
  const float* b_b = (const float*)d_in[7];
  const float* Wlin = (const float*)d_in[8];
  const float* blin = (const float*)d_in[9];
  float* out = (float*)d_out;

  const size_t HBUF_BYTES = (size_t)16 * 2 * 2048 * 8;      // 512 KiB
  const size_t HSUM_BYTES = (size_t)2 * B_ * H_ * 4;        // 256 KiB
  const size_t IMG_BYTES = (size_t)8 * 1024 * 512 * 16;     // 64 MiB
  if (ws_size < HBUF_BYTES + HSUM_BYTES) return;
  const bool prep = ws_size >= HBUF_BYTES + HSUM_BYTES + IMG_BYTES;

  char* ws = (char*)d_ws;
  unsigned long long* Hbuf = (unsigned long long*)ws;
  float* hsum = (float*)(ws + HBUF_BYTES);
  unsigned short* img = (unsigned short*)(ws + HBUF_BYTES + HSUM_BYTES);

  (void)hipMemsetAsync(Hbuf, 0, HBUF_BYTES, stream);  // tags start at 1; replay-safe
  if (prep) {
    prep_kernel<<<16384, 256, 0, stream>>>(emb, mask, img);
    rec_kernel<true><<<64, 512, 0, stream>>>(emb, mask, img, Wih_f, Whh_f, b_f,
                                             Wih_b, Whh_b, b_b, Hbuf, hsum);
  } else {
    rec_kernel<false><<<64, 512, 0, stream>>>(emb, mask, img, Wih_f, Whh_f, b_f,
                                              Wih_b, Whh_b, b_b, Hbuf, hsum);
  }
  head_kernel<<<1, 256, 0, stream>>>(hsum, Wlin, blin, out);
}